// Round 20
// baseline (477.206 us; speedup 1.0000x reference)
//
#include <hip/hip_runtime.h>

#define V_NODES 50000
#define FDIM    512   // B*Cin
#define CIN     128
#define COUT    128
#define BATCH   4
#define KORD    5
#define KTOT    (KORD * CIN)   // 640
#define SCAN_NBLK ((V_NODES + 255) / 256)   // 196
#define VB2     ((V_NODES + 127) / 128)     // 391
#define TQ2_BLOCKS (VB2 * (FDIM / 64))      // 391*8 = 3128
#define CONVW_BLOCKS ((KORD * COUT + 3) / 4) // 160

typedef float f32x4 __attribute__((ext_vector_type(4)));
typedef int   i32x4 __attribute__((ext_vector_type(4)));

struct EPair { float w; int c; };   // interleaved edge: weight + col

// ---------------- prep1: hist ∥ convw_q8 (block ranges) ---------------------
__global__ __launch_bounds__(256) void prep1_kernel(const int* __restrict__ rows,
                                                    int* __restrict__ cnt,
                                                    int E, int histBlocks,
                                                    const float* __restrict__ W,
                                                    signed char* __restrict__ Wq8,
                                                    float* __restrict__ Wsc) {
    const int bid = blockIdx.x;
    if (bid < histBlocks) {
        int e = bid * 256 + threadIdx.x;
        if (e < E) atomicAdd(&cnt[rows[e]], 1);
    } else {
        const int g = (bid - histBlocks) * 4 + (threadIdx.x >> 6);   // ord*128+co
        if (g >= KORD * COUT) return;
        const int co = g & 127;
        const int ord = g >> 7;
        const int lane = threadIdx.x & 63;
        float w0 = W[(size_t)(ord * 128 + lane * 2 + 0) * COUT + co];
        float w1 = W[(size_t)(ord * 128 + lane * 2 + 1) * COUT + co];
        float m = fmaxf(fabsf(w0), fabsf(w1));
        #pragma unroll
        for (int off = 1; off < 64; off <<= 1) m = fmaxf(m, __shfl_xor(m, off, 64));
        float inv = (m > 0.f) ? 127.f / m : 0.f;
        int q0 = max(-127, min(127, (int)rintf(w0 * inv)));
        int q1 = max(-127, min(127, (int)rintf(w1 * inv)));
        unsigned short pk = (unsigned short)((q0 & 0xff) | ((q1 & 0xff) << 8));
        *(unsigned short*)(Wq8 + (size_t)co * KTOT + ord * 128 + lane * 2) = pk;
        if (lane == 0) Wsc[ord * 128 + co] = m / 127.f;
    }
}

// ---------------- scans ------------------------------------------------------
__global__ __launch_bounds__(256) void scan1_kernel(const int* __restrict__ cnt,
                                                    int* __restrict__ rowPtr,
                                                    int* __restrict__ blkSum) {
    __shared__ int sh[256];
    const int t = threadIdx.x;
    const int i = blockIdx.x * 256 + t;
    int v = (i < V_NODES) ? cnt[i] : 0;
    sh[t] = v;
    __syncthreads();
    #pragma unroll
    for (int off = 1; off < 256; off <<= 1) {
        int u = (t >= off) ? sh[t - off] : 0;
        __syncthreads();
        sh[t] += u;
        __syncthreads();
    }
    if (i < V_NODES) rowPtr[i] = sh[t] - v;
    if (t == 255) blkSum[blockIdx.x] = sh[255];
}

__global__ __launch_bounds__(256) void scan23_kernel(const int* __restrict__ blkSum,
                                                     int* __restrict__ rowPtr,
                                                     int* __restrict__ cursor) {
    __shared__ int sh[256];
    const int t = threadIdx.x;
    int v = (t < SCAN_NBLK) ? blkSum[t] : 0;
    sh[t] = v;
    __syncthreads();
    #pragma unroll
    for (int off = 1; off < 256; off <<= 1) {
        int u = (t >= off) ? sh[t - off] : 0;
        __syncthreads();
        sh[t] += u;
        __syncthreads();
    }
    const int boff = sh[blockIdx.x] - blkSum[blockIdx.x];
    const int i = blockIdx.x * 256 + t;
    if (i < V_NODES) {
        int r = rowPtr[i] + boff;
        rowPtr[i] = r;
        cursor[i] = r;
    }
    if (blockIdx.x == 0 && t == 255) rowPtr[V_NODES] = sh[255];
}

// ---------------- prep2: scatter (FIRST) ∥ LDS-transpose quantize ------------
// quant tile 64 r x 128 v: coalesced f32x4 -> LDS [64][129] f32 (pad: free
// writes); thread owns (v, half-of-r): 32 stride-129 scalar reads (2-way =
// free), max in regs, shfl_xor(1) merge, quantize from regs, one 32B store.
__global__ __launch_bounds__(256) void prep2_kernel(const float* __restrict__ x,
                                                    signed char* __restrict__ xi,
                                                    float* __restrict__ scChunk,
                                                    const float* __restrict__ vals,
                                                    const int* __restrict__ rows,
                                                    const int* __restrict__ cols,
                                                    int* __restrict__ cursor,
                                                    EPair* __restrict__ ep,
                                                    int E, int scatBlocks) {
    __shared__ float tile[64][129];         // 33 KB
    const int bid = blockIdx.x;
    if (bid < scatBlocks) {
        // ---- scatter edges into CSR slots (starts at t=0, overlaps quant) ----
        int e = bid * 256 + threadIdx.x;
        if (e >= E) return;
        int r = rows[e];
        int pos = atomicAdd(&cursor[r], 1);
        EPair p; p.w = vals[e]; p.c = cols[e];
        ep[pos] = p;
        return;
    }
    const int qb = bid - scatBlocks;
    const int vb = qb % VB2;
    const int rb = qb / VB2;              // chunk 0..7
    const int v0 = vb * 128, r0 = rb * 64;
    const int t = threadIdx.x;

    // phase 1: coalesced load -> LDS (8 rows per 256-thread pass)
    {
        const int vg = t & 31;            // v-group (4 floats)
        const int rr = t >> 5;            // 0..7
        int vbase = v0 + vg * 4;
        if (vbase > V_NODES - 4) vbase = V_NODES - 4;
        #pragma unroll
        for (int it = 0; it < 8; ++it) {
            const int r = r0 + it * 8 + rr;
            f32x4 xv = *(const f32x4*)(x + (size_t)r * V_NODES + vbase);
            *(f32x4*)(&tile[it * 8 + rr][vg * 4]) = xv;
        }
    }
    __syncthreads();

    // phase 2: per-column max (32 values in registers)
    const int vloc = t >> 1;              // 0..127
    const int half = t & 1;
    float rv[32];
    float m = 0.f;
    #pragma unroll
    for (int i = 0; i < 32; ++i) {
        rv[i] = tile[half * 32 + i][vloc];
        m = fmaxf(m, fabsf(rv[i]));
    }
    m = fmaxf(m, __shfl_xor(m, 1, 64));   // merge halves (partner shares vloc)
    const float inv = (m > 0.f) ? 127.f / m : 0.f;
    const int v = v0 + vloc;
    if (half == 0 && v < V_NODES)
        scChunk[(size_t)rb * V_NODES + v] = m / 127.f;

    // phase 3: quantize from registers; one contiguous 32B store
    if (v < V_NODES) {
        unsigned int ow[8];
        #pragma unroll
        for (int k = 0; k < 8; ++k) {
            unsigned int pk = 0;
            #pragma unroll
            for (int b = 0; b < 4; ++b) {
                int q = (int)rintf(rv[k * 4 + b] * inv);
                q = max(-127, min(127, q));
                pk |= ((unsigned int)(q & 0xff)) << (8 * b);
            }
            ow[k] = pk;
        }
        uint4* dst = (uint4*)(xi + (size_t)v * FDIM + r0 + half * 32);
        uint4 o0; o0.x = ow[0]; o0.y = ow[1]; o0.z = ow[2]; o0.w = ow[3];
        uint4 o1; o1.x = ow[4]; o1.y = ow[5]; o1.z = ow[6]; o1.w = ow[7];
        dst[0] = o0;
        dst[1] = o1;
    }
}

// ---------------- CSR SpMM: i8 in, i8 out; optional chunked scales ----------
__global__ __launch_bounds__(256) void spmm_i8_kernel(const EPair* __restrict__ ep,
                                                      const int* __restrict__ rowPtr,
                                                      const signed char* __restrict__ xi,
                                                      const float* __restrict__ xsc,
                                                      const signed char* __restrict__ oldi,
                                                      const float* __restrict__ oldsc,
                                                      signed char* __restrict__ yi,
                                                      float* __restrict__ ysc,
                                                      float alpha, int beta,
                                                      int xChunked, int oldChunked) {
    const int wid = threadIdx.x >> 6;
    const int lane = threadIdx.x & 63;
    const int row = blockIdx.x * 4 + wid;
    if (row >= V_NODES) return;
    const int s = rowPtr[row], e_end = rowPtr[row + 1];
    const uint2* __restrict__ xq = (const uint2*)xi;   // 64 x 8B per row
    const float* __restrict__ xscl = xsc + (xChunked ? (size_t)(lane >> 3) * V_NODES : 0);
    const float* __restrict__ oscl = oldsc + (oldChunked ? (size_t)(lane >> 3) * V_NODES : 0);

    float acc[8];
    #pragma unroll
    for (int j = 0; j < 8; ++j) acc[j] = 0.f;

    int e = s;
    for (; e + 3 < e_end; e += 4) {
        EPair p[4];
        #pragma unroll
        for (int i = 0; i < 4; ++i) p[i] = ep[e + i];
        float w[4];
        #pragma unroll
        for (int i = 0; i < 4; ++i) w[i] = p[i].w * xscl[p[i].c];
        uint2 q[4];
        #pragma unroll
        for (int i = 0; i < 4; ++i) q[i] = xq[(size_t)p[i].c * 64 + lane];
        #pragma unroll
        for (int i = 0; i < 4; ++i) {
            #pragma unroll
            for (int wd = 0; wd < 2; ++wd) {
                unsigned int uu = wd ? q[i].y : q[i].x;
                #pragma unroll
                for (int b = 0; b < 4; ++b) {
                    float xv = (float)((signed char)(uu >> (8 * b)));
                    acc[wd * 4 + b] += w[i] * xv;
                }
            }
        }
    }
    for (; e < e_end; ++e) {
        EPair p0 = ep[e];
        float w0 = p0.w * xscl[p0.c];
        uint2 q0 = xq[(size_t)p0.c * 64 + lane];
        #pragma unroll
        for (int wd = 0; wd < 2; ++wd) {
            unsigned int uu = wd ? q0.y : q0.x;
            #pragma unroll
            for (int b = 0; b < 4; ++b) {
                float xv = (float)((signed char)(uu >> (8 * b)));
                acc[wd * 4 + b] += w0 * xv;
            }
        }
    }

    float r[8];
    #pragma unroll
    for (int j = 0; j < 8; ++j) r[j] = alpha * acc[j];
    if (beta) {
        uint2 q = ((const uint2*)oldi)[(size_t)row * 64 + lane];
        const float os = oscl[row];
        #pragma unroll
        for (int wd = 0; wd < 2; ++wd) {
            unsigned int uu = wd ? q.y : q.x;
            #pragma unroll
            for (int b = 0; b < 4; ++b)
                r[wd * 4 + b] -= os * (float)((signed char)(uu >> (8 * b)));
        }
    }

    float m = 0.f;
    #pragma unroll
    for (int j = 0; j < 8; ++j) m = fmaxf(m, fabsf(r[j]));
    #pragma unroll
    for (int off = 1; off < 64; off <<= 1) m = fmaxf(m, __shfl_xor(m, off, 64));
    float inv = (m > 0.f) ? 127.f / m : 0.f;
    unsigned int ow[2] = {0u, 0u};
    #pragma unroll
    for (int j = 0; j < 8; ++j) {
        int si = (int)rintf(r[j] * inv);
        si = max(-127, min(127, si));
        ow[j >> 2] |= ((unsigned int)(si & 0xff)) << (8 * (j & 3));
    }
    uint2 oi; oi.x = ow[0]; oi.y = ow[1];
    ((uint2*)yi)[(size_t)row * 64 + lane] = oi;
    if (lane == 0) ysc[row] = m / 127.f;
}

// ---------------- fused i8-MFMA GEMM, 8 waves (2v x 4co) --------------------
__global__ __launch_bounds__(512) void gemm_mfma_kernel(const signed char* __restrict__ Ti8,
                                                        const float* __restrict__ Tsc,
                                                        const signed char* __restrict__ Wq8,
                                                        const float* __restrict__ Wsc,
                                                        const float* __restrict__ bias,
                                                        float* __restrict__ out) {
    __shared__ signed char Abuf[3][128 * 64];   // 3 x 8 KB ring
    const int tid = threadIdx.x;
    const int lane = tid & 63;
    const int wid = tid >> 6;        // 0..7
    const int wr = wid >> 2;         // 0..1: v-half
    const int wc = wid & 3;          // 0..3: co-quarter
    const int v0 = blockIdx.x * 128;
    const int b = blockIdx.y;
    const int lr = lane & 15;
    const int lk = lane >> 4;

    size_t gof;
    {
        int rl = tid >> 2;           // 0..127
        int ch = tid & 3;
        int rowg = v0 + rl;
        if (rowg >= V_NODES) rowg = V_NODES - 1;
        int srcch = (ch - ((rl >> 1) & 3)) & 3;
        gof = (size_t)rowg * FDIM + b * CIN + (size_t)(srcch << 4);
    }

    f32x4 accF[4][2];
    #pragma unroll
    for (int mf = 0; mf < 4; ++mf)
        #pragma unroll
        for (int nf = 0; nf < 2; ++nf)
            accF[mf][nf] = (f32x4){0.f, 0.f, 0.f, 0.f};

    const signed char* Bb = Wq8 + (size_t)(wc * 32 + lr) * KTOT + lk * 16;

    // prologue: stage steps 0,1; preload B(0)
    #pragma unroll
    for (int st = 0; st < 2; ++st) {
        const size_t soff = (size_t)(st & 1) * 64;
        __builtin_amdgcn_global_load_lds(
            (const __attribute__((address_space(1))) void*)(Ti8 + gof + soff),
            (__attribute__((address_space(3))) void*)(&Abuf[st][tid * 16]),
            16, 0, 0);
    }
    i32x4 bcur[2];
    #pragma unroll
    for (int nf = 0; nf < 2; ++nf)
        bcur[nf] = *(const i32x4*)(Bb + (size_t)nf * 16 * KTOT);
    asm volatile("s_waitcnt vmcnt(0)" ::: "memory");
    asm volatile("s_barrier" ::: "memory");

    int curm = 0, stm = 2;
    #pragma unroll 1
    for (int s = 0; s < 10; ++s) {
        const int ord = s >> 1;
        // 1) scale loads for THIS step — issued first (oldest in vmcnt FIFO)
        const float* svp = (ord == 0)
            ? (Tsc + (size_t)(b * 2 + (s & 1)) * V_NODES)          // T0 chunk
            : (Tsc + (size_t)(7 + ord) * V_NODES);                 // per-row
        f32x4 sv[4];
        #pragma unroll
        for (int mf = 0; mf < 4; ++mf) {
            int base = v0 + wr * 64 + mf * 16 + lk * 4;
            if (base > V_NODES - 4) base = V_NODES - 4;
            sv[mf] = *(const f32x4*)(svp + base);
        }
        float swv0 = Wsc[ord * 128 + wc * 32 + lr];
        float swv1 = Wsc[ord * 128 + wc * 32 + 16 + lr];
        // 2) prefetch B(s+1)
        i32x4 bnxt[2];
        if (s < 9) {
            #pragma unroll
            for (int nf = 0; nf < 2; ++nf)
                bnxt[nf] = *(const i32x4*)(Bb + (size_t)nf * 16 * KTOT + (s + 1) * 64);
        }
        __builtin_amdgcn_sched_barrier(0);
        // 3) stage step s+2
        if (s < 8) {
            const int sn = s + 2;
            const size_t soff = (size_t)(sn >> 1) * ((size_t)V_NODES * FDIM) + (size_t)((sn & 1) * 64);
            __builtin_amdgcn_global_load_lds(
                (const __attribute__((address_space(1))) void*)(Ti8 + gof + soff),
                (__attribute__((address_space(3))) void*)(&Abuf[stm][tid * 16]),
                16, 0, 0);
        }
        // 4) compute: b128 rotated A reads -> i8 MFMA (C = 0), rescale per step
        const signed char* Ab = &Abuf[curm][0];
        i32x4 a[4];
        #pragma unroll
        for (int mf = 0; mf < 4; ++mf) {
            int rl = wr * 64 + mf * 16 + lr;
            int phys = rl * 64 + (((lk + (rl >> 1)) & 3) << 4);
            a[mf] = *(const i32x4*)(Ab + phys);
        }
        const i32x4 zero = (i32x4){0, 0, 0, 0};
        #pragma unroll
        for (int mf = 0; mf < 4; ++mf)
            #pragma unroll
            for (int nf = 0; nf < 2; ++nf) {
                i32x4 r = __builtin_amdgcn_mfma_i32_16x16x64_i8(a[mf], bcur[nf], zero, 0, 0, 0);
                float sw = nf ? swv1 : swv0;
                #pragma unroll
                for (int e = 0; e < 4; ++e)
                    accF[mf][nf][e] += (float)r[e] * (sv[mf][e] * sw);
            }
        // 5) copy prefetched B (its wait drains B(s+1)+stage(s+1))
        if (s < 9) {
            bcur[0] = bnxt[0];
            bcur[1] = bnxt[1];
        }
        asm volatile("s_barrier" ::: "memory");
        curm = (curm == 2) ? 0 : curm + 1;
        stm  = (stm == 2) ? 0 : stm + 1;
    }

    // --- epilogue: transpose through LDS (reuse ring), coalesced f32x4 stores
    float* lds_f = (float*)&Abuf[0][0];            // 32 co x 132 f32 = 16.9 KB < 24 KB
    const float bs0 = bias[wc * 32 + lr];
    const float bs1 = bias[wc * 32 + 16 + lr];
    #pragma unroll
    for (int p = 0; p < 4; ++p) {
        if (wc == p) {
            #pragma unroll
            for (int mf = 0; mf < 4; ++mf)
                #pragma unroll
                for (int nf = 0; nf < 2; ++nf) {
                    int co_l = nf * 16 + lr;
                    int vbase = wr * 64 + mf * 16 + lk * 4;
                    f32x4 val = accF[mf][nf];
                    float bs = nf ? bs1 : bs0;
                    val[0] += bs; val[1] += bs; val[2] += bs; val[3] += bs;
                    *(f32x4*)(lds_f + co_l * 132 + vbase) = val;
                }
        }
        __syncthreads();
        #pragma unroll
        for (int i = 0; i < 2; ++i) {
            int flat = i * 512 + tid;
            int co_l = flat >> 5;
            int v4 = flat & 31;
            int v = v0 + v4 * 4;
            if (v < V_NODES) {
                f32x4 val = *(const f32x4*)(lds_f + co_l * 132 + v4 * 4);
                *(f32x4*)(out + (size_t)(b * COUT + p * 32 + co_l) * V_NODES + v) = val;
            }
        }
        __syncthreads();
    }
}

extern "C" void kernel_launch(void* const* d_in, const int* in_sizes, int n_in,
                              void* d_out, int out_size, void* d_ws, size_t ws_size,
                              hipStream_t stream) {
    const float* x    = (const float*)d_in[0];
    const float* vals = (const float*)d_in[1];
    const float* W    = (const float*)d_in[2];
    const float* bias = (const float*)d_in[3];
    const int* rows   = (const int*)d_in[4];
    const int* cols   = (const int*)d_in[5];
    const int E = in_sizes[1];
    float* out = (float*)d_out;

    // workspace: i8 T0..T4, Tsc (scChunk[8][V] + sc1..sc4 [V]), Wq8, Wsc, edges, CSR
    signed char* i8T = (signed char*)d_ws;                             // 5 * V*512
    float* Tsc = (float*)(i8T + (size_t)KORD * V_NODES * FDIM);        // 12*V + 64 pad
    signed char* Wq8 = (signed char*)(Tsc + 12 * (size_t)V_NODES + 64);   // 128*640
    float* Wsc = (float*)(Wq8 + (size_t)COUT * KTOT);                  // 640
    EPair* ep     = (EPair*)(Wsc + KORD * COUT);
    int*   rowPtr = (int*)(ep + E);
    int*   cursor = rowPtr + V_NODES + 1;
    int*   cnt    = cursor + V_NODES;
    int*   blkSum = cnt + V_NODES;            // SCAN_NBLK

    signed char* i8T0 = i8T;
    signed char* i8T1 = i8T + 1 * (size_t)V_NODES * FDIM;
    signed char* i8T2 = i8T + 2 * (size_t)V_NODES * FDIM;
    signed char* i8T3 = i8T + 3 * (size_t)V_NODES * FDIM;
    signed char* i8T4 = i8T + 4 * (size_t)V_NODES * FDIM;
    float* scC = Tsc;                                  // [8][V] chunked T0 scales
    float* sc1 = Tsc + 8 * (size_t)V_NODES;
    float* sc2 = Tsc + 9 * (size_t)V_NODES;
    float* sc3 = Tsc + 10 * (size_t)V_NODES;
    float* sc4 = Tsc + 11 * (size_t)V_NODES;

    const int histBlocks = (E + 255) / 256;
    const int spB4 = (V_NODES + 3) / 4;

    // prep1: hist ∥ convw_q8
    hipMemsetAsync(cnt, 0, V_NODES * sizeof(int), stream);
    prep1_kernel<<<histBlocks + CONVW_BLOCKS, 256, 0, stream>>>(
        rows, cnt, E, histBlocks, W, Wq8, Wsc);
    scan1_kernel<<<SCAN_NBLK, 256, 0, stream>>>(cnt, rowPtr, blkSum);
    scan23_kernel<<<SCAN_NBLK, 256, 0, stream>>>(blkSum, rowPtr, cursor);
    // prep2: scatter (first) ∥ LDS-transpose quantize
    prep2_kernel<<<histBlocks + TQ2_BLOCKS, 256, 0, stream>>>(
        x, i8T0, scC, vals, rows, cols, cursor, ep, E, histBlocks);

    // Chebyshev recurrence — i8 state; T0 chunked scales, T1.. per-row
    spmm_i8_kernel<<<spB4, 256, 0, stream>>>(ep, rowPtr, i8T0, scC, i8T0, scC, i8T1, sc1, 1.f, 0, 1, 0);
    spmm_i8_kernel<<<spB4, 256, 0, stream>>>(ep, rowPtr, i8T1, sc1, i8T0, scC, i8T2, sc2, 2.f, 1, 0, 1);
    spmm_i8_kernel<<<spB4, 256, 0, stream>>>(ep, rowPtr, i8T2, sc2, i8T1, sc1, i8T3, sc3, 2.f, 1, 0, 0);
    spmm_i8_kernel<<<spB4, 256, 0, stream>>>(ep, rowPtr, i8T3, sc3, i8T2, sc2, i8T4, sc4, 2.f, 1, 0, 0);

    // fused contraction over all 5 orders (i8 MFMA, 8 waves, per-step rescale)
    dim3 gg((V_NODES + 127) / 128, BATCH);
    gemm_mfma_kernel<<<gg, 512, 0, stream>>>(i8T, Tsc, Wq8, Wsc, bias, out);
}

// Round 21
// 436.630 us; speedup vs baseline: 1.0929x; 1.0929x over previous
//
#include <hip/hip_runtime.h>

#define V_NODES 50000
#define FDIM    512   // B*Cin
#define CIN     128
#define COUT    128
#define BATCH   4
#define KORD    5
#define KTOT    (KORD * CIN)   // 640
#define SCAN_NBLK ((V_NODES + 255) / 256)   // 196
#define VB2     ((V_NODES + 127) / 128)     // 391
#define TQ2_BLOCKS (VB2 * (FDIM / 64))      // 391*8 = 3128
#define CONVW_BLOCKS ((KORD * COUT + 3) / 4) // 160

typedef float f32x4 __attribute__((ext_vector_type(4)));
typedef int   i32x4 __attribute__((ext_vector_type(4)));

struct EPair { float w; int c; };   // interleaved edge: weight + col

// ---------------- prep1: hist(+seq) ∥ convw_q8 (block ranges) ----------------
__global__ __launch_bounds__(256) void prep1_kernel(const int* __restrict__ rows,
                                                    int* __restrict__ cnt,
                                                    int* __restrict__ seq,
                                                    int E, int histBlocks,
                                                    const float* __restrict__ W,
                                                    signed char* __restrict__ Wq8,
                                                    float* __restrict__ Wsc) {
    const int bid = blockIdx.x;
    if (bid < histBlocks) {
        int e = bid * 256 + threadIdx.x;
        if (e < E) seq[e] = atomicAdd(&cnt[rows[e]], 1);   // keep the return!
    } else {
        const int g = (bid - histBlocks) * 4 + (threadIdx.x >> 6);   // ord*128+co
        if (g >= KORD * COUT) return;
        const int co = g & 127;
        const int ord = g >> 7;
        const int lane = threadIdx.x & 63;
        float w0 = W[(size_t)(ord * 128 + lane * 2 + 0) * COUT + co];
        float w1 = W[(size_t)(ord * 128 + lane * 2 + 1) * COUT + co];
        float m = fmaxf(fabsf(w0), fabsf(w1));
        #pragma unroll
        for (int off = 1; off < 64; off <<= 1) m = fmaxf(m, __shfl_xor(m, off, 64));
        float inv = (m > 0.f) ? 127.f / m : 0.f;
        int q0 = max(-127, min(127, (int)rintf(w0 * inv)));
        int q1 = max(-127, min(127, (int)rintf(w1 * inv)));
        unsigned short pk = (unsigned short)((q0 & 0xff) | ((q1 & 0xff) << 8));
        *(unsigned short*)(Wq8 + (size_t)co * KTOT + ord * 128 + lane * 2) = pk;
        if (lane == 0) Wsc[ord * 128 + co] = m / 127.f;
    }
}

// ---------------- scans ------------------------------------------------------
__global__ __launch_bounds__(256) void scan1_kernel(const int* __restrict__ cnt,
                                                    int* __restrict__ rowPtr,
                                                    int* __restrict__ blkSum) {
    __shared__ int sh[256];
    const int t = threadIdx.x;
    const int i = blockIdx.x * 256 + t;
    int v = (i < V_NODES) ? cnt[i] : 0;
    sh[t] = v;
    __syncthreads();
    #pragma unroll
    for (int off = 1; off < 256; off <<= 1) {
        int u = (t >= off) ? sh[t - off] : 0;
        __syncthreads();
        sh[t] += u;
        __syncthreads();
    }
    if (i < V_NODES) rowPtr[i] = sh[t] - v;
    if (t == 255) blkSum[blockIdx.x] = sh[255];
}

__global__ __launch_bounds__(256) void scan23_kernel(const int* __restrict__ blkSum,
                                                     int* __restrict__ rowPtr) {
    __shared__ int sh[256];
    const int t = threadIdx.x;
    int v = (t < SCAN_NBLK) ? blkSum[t] : 0;
    sh[t] = v;
    __syncthreads();
    #pragma unroll
    for (int off = 1; off < 256; off <<= 1) {
        int u = (t >= off) ? sh[t - off] : 0;
        __syncthreads();
        sh[t] += u;
        __syncthreads();
    }
    const int boff = sh[blockIdx.x] - blkSum[blockIdx.x];
    const int i = blockIdx.x * 256 + t;
    if (i < V_NODES) rowPtr[i] += boff;
    if (blockIdx.x == 0 && t == 255) rowPtr[V_NODES] = sh[255];
}

// ---------------- prep2: atomic-free scatter ∥ LDS-transpose quantize --------
__global__ __launch_bounds__(256) void prep2_kernel(const float* __restrict__ x,
                                                    signed char* __restrict__ xi,
                                                    float* __restrict__ scChunk,
                                                    const float* __restrict__ vals,
                                                    const int* __restrict__ rows,
                                                    const int* __restrict__ cols,
                                                    const int* __restrict__ rowPtr,
                                                    const int* __restrict__ seq,
                                                    EPair* __restrict__ ep,
                                                    int E, int scatBlocks) {
    __shared__ float tile[64][129];         // 33 KB
    const int bid = blockIdx.x;
    if (bid < scatBlocks) {
        // ---- atomic-free scatter: pos = rowPtr[row] + seq[e] ----
        int e = bid * 256 + threadIdx.x;
        if (e >= E) return;
        int r = rows[e];
        int pos = rowPtr[r] + seq[e];
        EPair p; p.w = vals[e]; p.c = cols[e];
        ep[pos] = p;
        return;
    }
    const int qb = bid - scatBlocks;
    const int vb = qb % VB2;
    const int rb = qb / VB2;              // chunk 0..7
    const int v0 = vb * 128, r0 = rb * 64;
    const int t = threadIdx.x;

    // phase 1: coalesced load -> LDS (8 rows per 256-thread pass)
    {
        const int vg = t & 31;            // v-group (4 floats)
        const int rr = t >> 5;            // 0..7
        int vbase = v0 + vg * 4;
        if (vbase > V_NODES - 4) vbase = V_NODES - 4;
        #pragma unroll
        for (int it = 0; it < 8; ++it) {
            const int r = r0 + it * 8 + rr;
            f32x4 xv = *(const f32x4*)(x + (size_t)r * V_NODES + vbase);
            *(f32x4*)(&tile[it * 8 + rr][vg * 4]) = xv;
        }
    }
    __syncthreads();

    // phase 2: per-column max (32 values in registers)
    const int vloc = t >> 1;              // 0..127
    const int half = t & 1;
    float rv[32];
    float m = 0.f;
    #pragma unroll
    for (int i = 0; i < 32; ++i) {
        rv[i] = tile[half * 32 + i][vloc];
        m = fmaxf(m, fabsf(rv[i]));
    }
    m = fmaxf(m, __shfl_xor(m, 1, 64));   // merge halves (partner shares vloc)
    const float inv = (m > 0.f) ? 127.f / m : 0.f;
    const int v = v0 + vloc;
    if (half == 0 && v < V_NODES)
        scChunk[(size_t)rb * V_NODES + v] = m / 127.f;

    // phase 3: quantize from registers; one contiguous 32B store
    if (v < V_NODES) {
        unsigned int ow[8];
        #pragma unroll
        for (int k = 0; k < 8; ++k) {
            unsigned int pk = 0;
            #pragma unroll
            for (int b = 0; b < 4; ++b) {
                int q = (int)rintf(rv[k * 4 + b] * inv);
                q = max(-127, min(127, q));
                pk |= ((unsigned int)(q & 0xff)) << (8 * b);
            }
            ow[k] = pk;
        }
        uint4* dst = (uint4*)(xi + (size_t)v * FDIM + r0 + half * 32);
        uint4 o0; o0.x = ow[0]; o0.y = ow[1]; o0.z = ow[2]; o0.w = ow[3];
        uint4 o1; o1.x = ow[4]; o1.y = ow[5]; o1.z = ow[6]; o1.w = ow[7];
        dst[0] = o0;
        dst[1] = o1;
    }
}

// ---------------- CSR SpMM: i8 in, i8 out; optional chunked scales ----------
__global__ __launch_bounds__(256) void spmm_i8_kernel(const EPair* __restrict__ ep,
                                                      const int* __restrict__ rowPtr,
                                                      const signed char* __restrict__ xi,
                                                      const float* __restrict__ xsc,
                                                      const signed char* __restrict__ oldi,
                                                      const float* __restrict__ oldsc,
                                                      signed char* __restrict__ yi,
                                                      float* __restrict__ ysc,
                                                      float alpha, int beta,
                                                      int xChunked, int oldChunked) {
    const int wid = threadIdx.x >> 6;
    const int lane = threadIdx.x & 63;
    const int row = blockIdx.x * 4 + wid;
    if (row >= V_NODES) return;
    const int s = rowPtr[row], e_end = rowPtr[row + 1];
    const uint2* __restrict__ xq = (const uint2*)xi;   // 64 x 8B per row
    const float* __restrict__ xscl = xsc + (xChunked ? (size_t)(lane >> 3) * V_NODES : 0);
    const float* __restrict__ oscl = oldsc + (oldChunked ? (size_t)(lane >> 3) * V_NODES : 0);

    float acc[8];
    #pragma unroll
    for (int j = 0; j < 8; ++j) acc[j] = 0.f;

    int e = s;
    for (; e + 3 < e_end; e += 4) {
        EPair p[4];
        #pragma unroll
        for (int i = 0; i < 4; ++i) p[i] = ep[e + i];
        float w[4];
        #pragma unroll
        for (int i = 0; i < 4; ++i) w[i] = p[i].w * xscl[p[i].c];
        uint2 q[4];
        #pragma unroll
        for (int i = 0; i < 4; ++i) q[i] = xq[(size_t)p[i].c * 64 + lane];
        #pragma unroll
        for (int i = 0; i < 4; ++i) {
            #pragma unroll
            for (int wd = 0; wd < 2; ++wd) {
                unsigned int uu = wd ? q[i].y : q[i].x;
                #pragma unroll
                for (int b = 0; b < 4; ++b) {
                    float xv = (float)((signed char)(uu >> (8 * b)));
                    acc[wd * 4 + b] += w[i] * xv;
                }
            }
        }
    }
    for (; e < e_end; ++e) {
        EPair p0 = ep[e];
        float w0 = p0.w * xscl[p0.c];
        uint2 q0 = xq[(size_t)p0.c * 64 + lane];
        #pragma unroll
        for (int wd = 0; wd < 2; ++wd) {
            unsigned int uu = wd ? q0.y : q0.x;
            #pragma unroll
            for (int b = 0; b < 4; ++b) {
                float xv = (float)((signed char)(uu >> (8 * b)));
                acc[wd * 4 + b] += w0 * xv;
            }
        }
    }

    float r[8];
    #pragma unroll
    for (int j = 0; j < 8; ++j) r[j] = alpha * acc[j];
    if (beta) {
        uint2 q = ((const uint2*)oldi)[(size_t)row * 64 + lane];
        const float os = oscl[row];
        #pragma unroll
        for (int wd = 0; wd < 2; ++wd) {
            unsigned int uu = wd ? q.y : q.x;
            #pragma unroll
            for (int b = 0; b < 4; ++b)
                r[wd * 4 + b] -= os * (float)((signed char)(uu >> (8 * b)));
        }
    }

    float m = 0.f;
    #pragma unroll
    for (int j = 0; j < 8; ++j) m = fmaxf(m, fabsf(r[j]));
    #pragma unroll
    for (int off = 1; off < 64; off <<= 1) m = fmaxf(m, __shfl_xor(m, off, 64));
    float inv = (m > 0.f) ? 127.f / m : 0.f;
    unsigned int ow[2] = {0u, 0u};
    #pragma unroll
    for (int j = 0; j < 8; ++j) {
        int si = (int)rintf(r[j] * inv);
        si = max(-127, min(127, si));
        ow[j >> 2] |= ((unsigned int)(si & 0xff)) << (8 * (j & 3));
    }
    uint2 oi; oi.x = ow[0]; oi.y = ow[1];
    ((uint2*)yi)[(size_t)row * 64 + lane] = oi;
    if (lane == 0) ysc[row] = m / 127.f;
}

// ---------------- fused i8-MFMA GEMM, 8 waves (2v x 4co) --------------------
__global__ __launch_bounds__(512) void gemm_mfma_kernel(const signed char* __restrict__ Ti8,
                                                        const float* __restrict__ Tsc,
                                                        const signed char* __restrict__ Wq8,
                                                        const float* __restrict__ Wsc,
                                                        const float* __restrict__ bias,
                                                        float* __restrict__ out) {
    __shared__ signed char Abuf[3][128 * 64];   // 3 x 8 KB ring
    const int tid = threadIdx.x;
    const int lane = tid & 63;
    const int wid = tid >> 6;        // 0..7
    const int wr = wid >> 2;         // 0..1: v-half
    const int wc = wid & 3;          // 0..3: co-quarter
    const int v0 = blockIdx.x * 128;
    const int b = blockIdx.y;
    const int lr = lane & 15;
    const int lk = lane >> 4;

    size_t gof;
    {
        int rl = tid >> 2;           // 0..127
        int ch = tid & 3;
        int rowg = v0 + rl;
        if (rowg >= V_NODES) rowg = V_NODES - 1;
        int srcch = (ch - ((rl >> 1) & 3)) & 3;
        gof = (size_t)rowg * FDIM + b * CIN + (size_t)(srcch << 4);
    }

    f32x4 accF[4][2];
    #pragma unroll
    for (int mf = 0; mf < 4; ++mf)
        #pragma unroll
        for (int nf = 0; nf < 2; ++nf)
            accF[mf][nf] = (f32x4){0.f, 0.f, 0.f, 0.f};

    const signed char* Bb = Wq8 + (size_t)(wc * 32 + lr) * KTOT + lk * 16;

    // prologue: stage steps 0,1; preload B(0)
    #pragma unroll
    for (int st = 0; st < 2; ++st) {
        const size_t soff = (size_t)(st & 1) * 64;
        __builtin_amdgcn_global_load_lds(
            (const __attribute__((address_space(1))) void*)(Ti8 + gof + soff),
            (__attribute__((address_space(3))) void*)(&Abuf[st][tid * 16]),
            16, 0, 0);
    }
    i32x4 bcur[2];
    #pragma unroll
    for (int nf = 0; nf < 2; ++nf)
        bcur[nf] = *(const i32x4*)(Bb + (size_t)nf * 16 * KTOT);
    asm volatile("s_waitcnt vmcnt(0)" ::: "memory");
    asm volatile("s_barrier" ::: "memory");

    int curm = 0, stm = 2;
    #pragma unroll 1
    for (int s = 0; s < 10; ++s) {
        const int ord = s >> 1;
        // 1) scale loads for THIS step — issued first (oldest in vmcnt FIFO)
        const float* svp = (ord == 0)
            ? (Tsc + (size_t)(b * 2 + (s & 1)) * V_NODES)          // T0 chunk
            : (Tsc + (size_t)(7 + ord) * V_NODES);                 // per-row
        f32x4 sv[4];
        #pragma unroll
        for (int mf = 0; mf < 4; ++mf) {
            int base = v0 + wr * 64 + mf * 16 + lk * 4;
            if (base > V_NODES - 4) base = V_NODES - 4;
            sv[mf] = *(const f32x4*)(svp + base);
        }
        float swv0 = Wsc[ord * 128 + wc * 32 + lr];
        float swv1 = Wsc[ord * 128 + wc * 32 + 16 + lr];
        // 2) prefetch B(s+1)
        i32x4 bnxt[2];
        if (s < 9) {
            #pragma unroll
            for (int nf = 0; nf < 2; ++nf)
                bnxt[nf] = *(const i32x4*)(Bb + (size_t)nf * 16 * KTOT + (s + 1) * 64);
        }
        __builtin_amdgcn_sched_barrier(0);
        // 3) stage step s+2
        if (s < 8) {
            const int sn = s + 2;
            const size_t soff = (size_t)(sn >> 1) * ((size_t)V_NODES * FDIM) + (size_t)((sn & 1) * 64);
            __builtin_amdgcn_global_load_lds(
                (const __attribute__((address_space(1))) void*)(Ti8 + gof + soff),
                (__attribute__((address_space(3))) void*)(&Abuf[stm][tid * 16]),
                16, 0, 0);
        }
        // 4) compute: b128 rotated A reads -> i8 MFMA (C = 0), rescale per step
        const signed char* Ab = &Abuf[curm][0];
        i32x4 a[4];
        #pragma unroll
        for (int mf = 0; mf < 4; ++mf) {
            int rl = wr * 64 + mf * 16 + lr;
            int phys = rl * 64 + (((lk + (rl >> 1)) & 3) << 4);
            a[mf] = *(const i32x4*)(Ab + phys);
        }
        const i32x4 zero = (i32x4){0, 0, 0, 0};
        #pragma unroll
        for (int mf = 0; mf < 4; ++mf)
            #pragma unroll
            for (int nf = 0; nf < 2; ++nf) {
                i32x4 r = __builtin_amdgcn_mfma_i32_16x16x64_i8(a[mf], bcur[nf], zero, 0, 0, 0);
                float sw = nf ? swv1 : swv0;
                #pragma unroll
                for (int e = 0; e < 4; ++e)
                    accF[mf][nf][e] += (float)r[e] * (sv[mf][e] * sw);
            }
        // 5) copy prefetched B (its wait drains B(s+1)+stage(s+1))
        if (s < 9) {
            bcur[0] = bnxt[0];
            bcur[1] = bnxt[1];
        }
        asm volatile("s_barrier" ::: "memory");
        curm = (curm == 2) ? 0 : curm + 1;
        stm  = (stm == 2) ? 0 : stm + 1;
    }

    // --- epilogue: transpose through LDS (reuse ring), coalesced f32x4 stores
    float* lds_f = (float*)&Abuf[0][0];            // 32 co x 132 f32 = 16.9 KB < 24 KB
    const float bs0 = bias[wc * 32 + lr];
    const float bs1 = bias[wc * 32 + 16 + lr];
    #pragma unroll
    for (int p = 0; p < 4; ++p) {
        if (wc == p) {
            #pragma unroll
            for (int mf = 0; mf < 4; ++mf)
                #pragma unroll
                for (int nf = 0; nf < 2; ++nf) {
                    int co_l = nf * 16 + lr;
                    int vbase = wr * 64 + mf * 16 + lk * 4;
                    f32x4 val = accF[mf][nf];
                    float bs = nf ? bs1 : bs0;
                    val[0] += bs; val[1] += bs; val[2] += bs; val[3] += bs;
                    *(f32x4*)(lds_f + co_l * 132 + vbase) = val;
                }
        }
        __syncthreads();
        #pragma unroll
        for (int i = 0; i < 2; ++i) {
            int flat = i * 512 + tid;
            int co_l = flat >> 5;
            int v4 = flat & 31;
            int v = v0 + v4 * 4;
            if (v < V_NODES) {
                f32x4 val = *(const f32x4*)(lds_f + co_l * 132 + v4 * 4);
                *(f32x4*)(out + (size_t)(b * COUT + p * 32 + co_l) * V_NODES + v) = val;
            }
        }
        __syncthreads();
    }
}

extern "C" void kernel_launch(void* const* d_in, const int* in_sizes, int n_in,
                              void* d_out, int out_size, void* d_ws, size_t ws_size,
                              hipStream_t stream) {
    const float* x    = (const float*)d_in[0];
    const float* vals = (const float*)d_in[1];
    const float* W    = (const float*)d_in[2];
    const float* bias = (const float*)d_in[3];
    const int* rows   = (const int*)d_in[4];
    const int* cols   = (const int*)d_in[5];
    const int E = in_sizes[1];
    float* out = (float*)d_out;

    // workspace: i8 T0..T4, Tsc, Wq8, Wsc, edges, seq, CSR
    signed char* i8T = (signed char*)d_ws;                             // 5 * V*512
    float* Tsc = (float*)(i8T + (size_t)KORD * V_NODES * FDIM);        // 12*V + 64 pad
    signed char* Wq8 = (signed char*)(Tsc + 12 * (size_t)V_NODES + 64);   // 128*640
    float* Wsc = (float*)(Wq8 + (size_t)COUT * KTOT);                  // 640
    EPair* ep     = (EPair*)(Wsc + KORD * COUT);
    int*   seq    = (int*)(ep + E);           // E
    int*   rowPtr = seq + E;                  // V+1
    int*   cnt    = rowPtr + V_NODES + 1;     // V
    int*   blkSum = cnt + V_NODES;            // SCAN_NBLK

    signed char* i8T0 = i8T;
    signed char* i8T1 = i8T + 1 * (size_t)V_NODES * FDIM;
    signed char* i8T2 = i8T + 2 * (size_t)V_NODES * FDIM;
    signed char* i8T3 = i8T + 3 * (size_t)V_NODES * FDIM;
    signed char* i8T4 = i8T + 4 * (size_t)V_NODES * FDIM;
    float* scC = Tsc;                                  // [8][V] chunked T0 scales
    float* sc1 = Tsc + 8 * (size_t)V_NODES;
    float* sc2 = Tsc + 9 * (size_t)V_NODES;
    float* sc3 = Tsc + 10 * (size_t)V_NODES;
    float* sc4 = Tsc + 11 * (size_t)V_NODES;

    const int histBlocks = (E + 255) / 256;
    const int spB4 = (V_NODES + 3) / 4;

    // prep1: hist(+seq) ∥ convw_q8
    hipMemsetAsync(cnt, 0, V_NODES * sizeof(int), stream);
    prep1_kernel<<<histBlocks + CONVW_BLOCKS, 256, 0, stream>>>(
        rows, cnt, seq, E, histBlocks, W, Wq8, Wsc);
    scan1_kernel<<<SCAN_NBLK, 256, 0, stream>>>(cnt, rowPtr, blkSum);
    scan23_kernel<<<SCAN_NBLK, 256, 0, stream>>>(blkSum, rowPtr);
    // prep2: atomic-free scatter ∥ LDS-transpose quantize
    prep2_kernel<<<histBlocks + TQ2_BLOCKS, 256, 0, stream>>>(
        x, i8T0, scC, vals, rows, cols, rowPtr, seq, ep, E, histBlocks);

    // Chebyshev recurrence — i8 state; T0 chunked scales, T1.. per-row
    spmm_i8_kernel<<<spB4, 256, 0, stream>>>(ep, rowPtr, i8T0, scC, i8T0, scC, i8T1, sc1, 1.f, 0, 1, 0);
    spmm_i8_kernel<<<spB4, 256, 0, stream>>>(ep, rowPtr, i8T1, sc1, i8T0, scC, i8T2, sc2, 2.f, 1, 0, 1);
    spmm_i8_kernel<<<spB4, 256, 0, stream>>>(ep, rowPtr, i8T2, sc2, i8T1, sc1, i8T3, sc3, 2.f, 1, 0, 0);
    spmm_i8_kernel<<<spB4, 256, 0, stream>>>(ep, rowPtr, i8T3, sc3, i8T2, sc2, i8T4, sc4, 2.f, 1, 0, 0);

    // fused contraction over all 5 orders (i8 MFMA, 8 waves, per-step rescale)
    dim3 gg((V_NODES + 127) / 128, BATCH);
    gemm_mfma_kernel<<<gg, 512, 0, stream>>>(i8T, Tsc, Wq8, Wsc, bias, out);
}

// Round 22
// 430.723 us; speedup vs baseline: 1.1079x; 1.0137x over previous
//
#include <hip/hip_runtime.h>

#define V_NODES 50000
#define FDIM    512   // B*Cin
#define CIN     128
#define COUT    128
#define BATCH   4
#define KORD    5
#define KTOT    (KORD * CIN)   // 640
#define SCAN_NBLK ((V_NODES + 255) / 256)   // 196
#define VB2     ((V_NODES + 127) / 128)     // 391
#define TQ2_BLOCKS (VB2 * (FDIM / 64))      // 391*8 = 3128
#define CONVW_BLOCKS ((KORD * COUT + 3) / 4) // 160

typedef float f32x4 __attribute__((ext_vector_type(4)));
typedef int   i32x4 __attribute__((ext_vector_type(4)));

struct EPair { float w; int c; };   // interleaved edge: weight + col

// ---------------- prep1: hist(+seq) ∥ convw_q8 (block ranges) ----------------
__global__ __launch_bounds__(256) void prep1_kernel(const int* __restrict__ rows,
                                                    int* __restrict__ cnt,
                                                    int* __restrict__ seq,
                                                    int E, int histBlocks,
                                                    const float* __restrict__ W,
                                                    signed char* __restrict__ Wq8,
                                                    float* __restrict__ Wsc) {
    const int bid = blockIdx.x;
    if (bid < histBlocks) {
        int e = bid * 256 + threadIdx.x;
        if (e < E) seq[e] = atomicAdd(&cnt[rows[e]], 1);   // keep the return!
    } else {
        const int g = (bid - histBlocks) * 4 + (threadIdx.x >> 6);   // ord*128+co
        if (g >= KORD * COUT) return;
        const int co = g & 127;
        const int ord = g >> 7;
        const int lane = threadIdx.x & 63;
        float w0 = W[(size_t)(ord * 128 + lane * 2 + 0) * COUT + co];
        float w1 = W[(size_t)(ord * 128 + lane * 2 + 1) * COUT + co];
        float m = fmaxf(fabsf(w0), fabsf(w1));
        #pragma unroll
        for (int off = 1; off < 64; off <<= 1) m = fmaxf(m, __shfl_xor(m, off, 64));
        float inv = (m > 0.f) ? 127.f / m : 0.f;
        int q0 = max(-127, min(127, (int)rintf(w0 * inv)));
        int q1 = max(-127, min(127, (int)rintf(w1 * inv)));
        unsigned short pk = (unsigned short)((q0 & 0xff) | ((q1 & 0xff) << 8));
        *(unsigned short*)(Wq8 + (size_t)co * KTOT + ord * 128 + lane * 2) = pk;
        if (lane == 0) Wsc[ord * 128 + co] = m / 127.f;
    }
}

// ---------------- scans ------------------------------------------------------
__global__ __launch_bounds__(256) void scan1_kernel(const int* __restrict__ cnt,
                                                    int* __restrict__ rowPtr,
                                                    int* __restrict__ blkSum) {
    __shared__ int sh[256];
    const int t = threadIdx.x;
    const int i = blockIdx.x * 256 + t;
    int v = (i < V_NODES) ? cnt[i] : 0;
    sh[t] = v;
    __syncthreads();
    #pragma unroll
    for (int off = 1; off < 256; off <<= 1) {
        int u = (t >= off) ? sh[t - off] : 0;
        __syncthreads();
        sh[t] += u;
        __syncthreads();
    }
    if (i < V_NODES) rowPtr[i] = sh[t] - v;
    if (t == 255) blkSum[blockIdx.x] = sh[255];
}

__global__ __launch_bounds__(256) void scan23_kernel(const int* __restrict__ blkSum,
                                                     int* __restrict__ rowPtr) {
    __shared__ int sh[256];
    const int t = threadIdx.x;
    int v = (t < SCAN_NBLK) ? blkSum[t] : 0;
    sh[t] = v;
    __syncthreads();
    #pragma unroll
    for (int off = 1; off < 256; off <<= 1) {
        int u = (t >= off) ? sh[t - off] : 0;
        __syncthreads();
        sh[t] += u;
        __syncthreads();
    }
    const int boff = sh[blockIdx.x] - blkSum[blockIdx.x];
    const int i = blockIdx.x * 256 + t;
    if (i < V_NODES) rowPtr[i] += boff;
    if (blockIdx.x == 0 && t == 255) rowPtr[V_NODES] = sh[255];
}

// ---------------- prep2: atomic-free scatter ∥ LDS-transpose quantize --------
__global__ __launch_bounds__(256) void prep2_kernel(const float* __restrict__ x,
                                                    signed char* __restrict__ xi,
                                                    float* __restrict__ scChunk,
                                                    const float* __restrict__ vals,
                                                    const int* __restrict__ rows,
                                                    const int* __restrict__ cols,
                                                    const int* __restrict__ rowPtr,
                                                    const int* __restrict__ seq,
                                                    EPair* __restrict__ ep,
                                                    int E, int scatBlocks) {
    __shared__ float tile[64][129];         // 33 KB
    const int bid = blockIdx.x;
    if (bid < scatBlocks) {
        // ---- atomic-free scatter: pos = rowPtr[row] + seq[e] ----
        int e = bid * 256 + threadIdx.x;
        if (e >= E) return;
        int r = rows[e];
        int pos = rowPtr[r] + seq[e];
        EPair p; p.w = vals[e]; p.c = cols[e];
        ep[pos] = p;
        return;
    }
    const int qb = bid - scatBlocks;
    const int vb = qb % VB2;
    const int rb = qb / VB2;              // chunk 0..7
    const int v0 = vb * 128, r0 = rb * 64;
    const int t = threadIdx.x;

    // phase 1: coalesced load -> LDS (8 rows per 256-thread pass)
    {
        const int vg = t & 31;            // v-group (4 floats)
        const int rr = t >> 5;            // 0..7
        int vbase = v0 + vg * 4;
        if (vbase > V_NODES - 4) vbase = V_NODES - 4;
        #pragma unroll
        for (int it = 0; it < 8; ++it) {
            const int r = r0 + it * 8 + rr;
            f32x4 xv = *(const f32x4*)(x + (size_t)r * V_NODES + vbase);
            *(f32x4*)(&tile[it * 8 + rr][vg * 4]) = xv;
        }
    }
    __syncthreads();

    // phase 2: per-column max (32 values in registers)
    const int vloc = t >> 1;              // 0..127
    const int half = t & 1;
    float rv[32];
    float m = 0.f;
    #pragma unroll
    for (int i = 0; i < 32; ++i) {
        rv[i] = tile[half * 32 + i][vloc];
        m = fmaxf(m, fabsf(rv[i]));
    }
    m = fmaxf(m, __shfl_xor(m, 1, 64));   // merge halves (partner shares vloc)
    const float inv = (m > 0.f) ? 127.f / m : 0.f;
    const int v = v0 + vloc;
    if (half == 0 && v < V_NODES)
        scChunk[(size_t)rb * V_NODES + v] = m / 127.f;

    // phase 3: quantize from registers; one contiguous 32B store
    if (v < V_NODES) {
        unsigned int ow[8];
        #pragma unroll
        for (int k = 0; k < 8; ++k) {
            unsigned int pk = 0;
            #pragma unroll
            for (int b = 0; b < 4; ++b) {
                int q = (int)rintf(rv[k * 4 + b] * inv);
                q = max(-127, min(127, q));
                pk |= ((unsigned int)(q & 0xff)) << (8 * b);
            }
            ow[k] = pk;
        }
        uint4* dst = (uint4*)(xi + (size_t)v * FDIM + r0 + half * 32);
        uint4 o0; o0.x = ow[0]; o0.y = ow[1]; o0.z = ow[2]; o0.w = ow[3];
        uint4 o1; o1.x = ow[4]; o1.y = ow[5]; o1.z = ow[6]; o1.w = ow[7];
        dst[0] = o0;
        dst[1] = o1;
    }
}

// ---------------- CSR SpMM: i8 in, i8 out; optional chunked scales ----------
__global__ __launch_bounds__(256) void spmm_i8_kernel(const EPair* __restrict__ ep,
                                                      const int* __restrict__ rowPtr,
                                                      const signed char* __restrict__ xi,
                                                      const float* __restrict__ xsc,
                                                      const signed char* __restrict__ oldi,
                                                      const float* __restrict__ oldsc,
                                                      signed char* __restrict__ yi,
                                                      float* __restrict__ ysc,
                                                      float alpha, int beta,
                                                      int xChunked, int oldChunked) {
    const int wid = threadIdx.x >> 6;
    const int lane = threadIdx.x & 63;
    const int row = blockIdx.x * 4 + wid;
    if (row >= V_NODES) return;
    const int s = rowPtr[row], e_end = rowPtr[row + 1];
    const uint2* __restrict__ xq = (const uint2*)xi;   // 64 x 8B per row
    const float* __restrict__ xscl = xsc + (xChunked ? (size_t)(lane >> 3) * V_NODES : 0);
    const float* __restrict__ oscl = oldsc + (oldChunked ? (size_t)(lane >> 3) * V_NODES : 0);

    float acc[8];
    #pragma unroll
    for (int j = 0; j < 8; ++j) acc[j] = 0.f;

    int e = s;
    for (; e + 3 < e_end; e += 4) {
        EPair p[4];
        #pragma unroll
        for (int i = 0; i < 4; ++i) p[i] = ep[e + i];
        float w[4];
        #pragma unroll
        for (int i = 0; i < 4; ++i) w[i] = p[i].w * xscl[p[i].c];
        uint2 q[4];
        #pragma unroll
        for (int i = 0; i < 4; ++i) q[i] = xq[(size_t)p[i].c * 64 + lane];
        #pragma unroll
        for (int i = 0; i < 4; ++i) {
            #pragma unroll
            for (int wd = 0; wd < 2; ++wd) {
                unsigned int uu = wd ? q[i].y : q[i].x;
                #pragma unroll
                for (int b = 0; b < 4; ++b) {
                    float xv = (float)((signed char)(uu >> (8 * b)));
                    acc[wd * 4 + b] += w[i] * xv;
                }
            }
        }
    }
    for (; e < e_end; ++e) {
        EPair p0 = ep[e];
        float w0 = p0.w * xscl[p0.c];
        uint2 q0 = xq[(size_t)p0.c * 64 + lane];
        #pragma unroll
        for (int wd = 0; wd < 2; ++wd) {
            unsigned int uu = wd ? q0.y : q0.x;
            #pragma unroll
            for (int b = 0; b < 4; ++b) {
                float xv = (float)((signed char)(uu >> (8 * b)));
                acc[wd * 4 + b] += w0 * xv;
            }
        }
    }

    float r[8];
    #pragma unroll
    for (int j = 0; j < 8; ++j) r[j] = alpha * acc[j];
    if (beta) {
        uint2 q = ((const uint2*)oldi)[(size_t)row * 64 + lane];
        const float os = oscl[row];
        #pragma unroll
        for (int wd = 0; wd < 2; ++wd) {
            unsigned int uu = wd ? q.y : q.x;
            #pragma unroll
            for (int b = 0; b < 4; ++b)
                r[wd * 4 + b] -= os * (float)((signed char)(uu >> (8 * b)));
        }
    }

    float m = 0.f;
    #pragma unroll
    for (int j = 0; j < 8; ++j) m = fmaxf(m, fabsf(r[j]));
    #pragma unroll
    for (int off = 1; off < 64; off <<= 1) m = fmaxf(m, __shfl_xor(m, off, 64));
    float inv = (m > 0.f) ? 127.f / m : 0.f;
    unsigned int ow[2] = {0u, 0u};
    #pragma unroll
    for (int j = 0; j < 8; ++j) {
        int si = (int)rintf(r[j] * inv);
        si = max(-127, min(127, si));
        ow[j >> 2] |= ((unsigned int)(si & 0xff)) << (8 * (j & 3));
    }
    uint2 oi; oi.x = ow[0]; oi.y = ow[1];
    ((uint2*)yi)[(size_t)row * 64 + lane] = oi;
    if (lane == 0) ysc[row] = m / 127.f;
}

// ---------------- fused i8-MFMA GEMM, 8 waves (2v x 4co) --------------------
// Hybrid rescale: order 0 rescales per step (chunked scales differ per step);
// orders 1..4 accumulate i32 across their 2 steps and rescale once (s odd).
__global__ __launch_bounds__(512) void gemm_mfma_kernel(const signed char* __restrict__ Ti8,
                                                        const float* __restrict__ Tsc,
                                                        const signed char* __restrict__ Wq8,
                                                        const float* __restrict__ Wsc,
                                                        const float* __restrict__ bias,
                                                        float* __restrict__ out) {
    __shared__ signed char Abuf[3][128 * 64];   // 3 x 8 KB ring
    const int tid = threadIdx.x;
    const int lane = tid & 63;
    const int wid = tid >> 6;        // 0..7
    const int wr = wid >> 2;         // 0..1: v-half
    const int wc = wid & 3;          // 0..3: co-quarter
    const int v0 = blockIdx.x * 128;
    const int b = blockIdx.y;
    const int lr = lane & 15;
    const int lk = lane >> 4;

    size_t gof;
    {
        int rl = tid >> 2;           // 0..127
        int ch = tid & 3;
        int rowg = v0 + rl;
        if (rowg >= V_NODES) rowg = V_NODES - 1;
        int srcch = (ch - ((rl >> 1) & 3)) & 3;
        gof = (size_t)rowg * FDIM + b * CIN + (size_t)(srcch << 4);
    }

    f32x4 accF[4][2];
    i32x4 accI[4][2];
    #pragma unroll
    for (int mf = 0; mf < 4; ++mf)
        #pragma unroll
        for (int nf = 0; nf < 2; ++nf) {
            accF[mf][nf] = (f32x4){0.f, 0.f, 0.f, 0.f};
            accI[mf][nf] = (i32x4){0, 0, 0, 0};
        }

    const signed char* Bb = Wq8 + (size_t)(wc * 32 + lr) * KTOT + lk * 16;

    // prologue: stage steps 0,1; preload B(0)
    #pragma unroll
    for (int st = 0; st < 2; ++st) {
        const size_t soff = (size_t)(st & 1) * 64;
        __builtin_amdgcn_global_load_lds(
            (const __attribute__((address_space(1))) void*)(Ti8 + gof + soff),
            (__attribute__((address_space(3))) void*)(&Abuf[st][tid * 16]),
            16, 0, 0);
    }
    i32x4 bcur[2];
    #pragma unroll
    for (int nf = 0; nf < 2; ++nf)
        bcur[nf] = *(const i32x4*)(Bb + (size_t)nf * 16 * KTOT);
    asm volatile("s_waitcnt vmcnt(0)" ::: "memory");
    asm volatile("s_barrier" ::: "memory");

    int curm = 0, stm = 2;
    #pragma unroll 1
    for (int s = 0; s < 10; ++s) {
        const int ord = s >> 1;
        const bool rs = (s < 2) || (s & 1);    // rescale this step?
        // 1) scale loads — only on rescale steps, issued first (oldest in FIFO)
        f32x4 sv[4];
        float swv0 = 0.f, swv1 = 0.f;
        if (rs) {
            const float* svp = (s < 2)
                ? (Tsc + (size_t)(b * 2 + s) * V_NODES)        // T0 chunk b*2+s
                : (Tsc + (size_t)(7 + ord) * V_NODES);         // per-row
            #pragma unroll
            for (int mf = 0; mf < 4; ++mf) {
                int base = v0 + wr * 64 + mf * 16 + lk * 4;
                if (base > V_NODES - 4) base = V_NODES - 4;
                sv[mf] = *(const f32x4*)(svp + base);
            }
            swv0 = Wsc[ord * 128 + wc * 32 + lr];
            swv1 = Wsc[ord * 128 + wc * 32 + 16 + lr];
        }
        // 2) prefetch B(s+1)
        i32x4 bnxt[2];
        if (s < 9) {
            #pragma unroll
            for (int nf = 0; nf < 2; ++nf)
                bnxt[nf] = *(const i32x4*)(Bb + (size_t)nf * 16 * KTOT + (s + 1) * 64);
        }
        __builtin_amdgcn_sched_barrier(0);
        // 3) stage step s+2
        if (s < 8) {
            const int sn = s + 2;
            const size_t soff = (size_t)(sn >> 1) * ((size_t)V_NODES * FDIM) + (size_t)((sn & 1) * 64);
            __builtin_amdgcn_global_load_lds(
                (const __attribute__((address_space(1))) void*)(Ti8 + gof + soff),
                (__attribute__((address_space(3))) void*)(&Abuf[stm][tid * 16]),
                16, 0, 0);
        }
        // 4) compute: b128 rotated A reads -> i8 MFMA accumulating into accI
        const signed char* Ab = &Abuf[curm][0];
        i32x4 a[4];
        #pragma unroll
        for (int mf = 0; mf < 4; ++mf) {
            int rl = wr * 64 + mf * 16 + lr;
            int phys = rl * 64 + (((lk + (rl >> 1)) & 3) << 4);
            a[mf] = *(const i32x4*)(Ab + phys);
        }
        #pragma unroll
        for (int mf = 0; mf < 4; ++mf)
            #pragma unroll
            for (int nf = 0; nf < 2; ++nf)
                accI[mf][nf] = __builtin_amdgcn_mfma_i32_16x16x64_i8(a[mf], bcur[nf], accI[mf][nf], 0, 0, 0);
        // 5) rescale on rs steps; reset accI
        if (rs) {
            #pragma unroll
            for (int mf = 0; mf < 4; ++mf)
                #pragma unroll
                for (int nf = 0; nf < 2; ++nf) {
                    float sw = nf ? swv1 : swv0;
                    #pragma unroll
                    for (int e = 0; e < 4; ++e)
                        accF[mf][nf][e] += (float)accI[mf][nf][e] * (sv[mf][e] * sw);
                    accI[mf][nf] = (i32x4){0, 0, 0, 0};
                }
        }
        // 6) copy prefetched B (its wait drains B(s+1)+stage(s+1))
        if (s < 9) {
            bcur[0] = bnxt[0];
            bcur[1] = bnxt[1];
        }
        asm volatile("s_barrier" ::: "memory");
        curm = (curm == 2) ? 0 : curm + 1;
        stm  = (stm == 2) ? 0 : stm + 1;
    }

    // --- epilogue: transpose through LDS (reuse ring), coalesced f32x4 stores
    float* lds_f = (float*)&Abuf[0][0];            // 32 co x 132 f32 = 16.9 KB < 24 KB
    const float bs0 = bias[wc * 32 + lr];
    const float bs1 = bias[wc * 32 + 16 + lr];
    #pragma unroll
    for (int p = 0; p < 4; ++p) {
        if (wc == p) {
            #pragma unroll
            for (int mf = 0; mf < 4; ++mf)
                #pragma unroll
                for (int nf = 0; nf < 2; ++nf) {
                    int co_l = nf * 16 + lr;
                    int vbase = wr * 64 + mf * 16 + lk * 4;
                    f32x4 val = accF[mf][nf];
                    float bs = nf ? bs1 : bs0;
                    val[0] += bs; val[1] += bs; val[2] += bs; val[3] += bs;
                    *(f32x4*)(lds_f + co_l * 132 + vbase) = val;
                }
        }
        __syncthreads();
        #pragma unroll
        for (int i = 0; i < 2; ++i) {
            int flat = i * 512 + tid;
            int co_l = flat >> 5;
            int v4 = flat & 31;
            int v = v0 + v4 * 4;
            if (v < V_NODES) {
                f32x4 val = *(const f32x4*)(lds_f + co_l * 132 + v4 * 4);
                *(f32x4*)(out + (size_t)(b * COUT + p * 32 + co_l) * V_NODES + v) = val;
            }
        }
        __syncthreads();
    }
}

extern "C" void kernel_launch(void* const* d_in, const int* in_sizes, int n_in,
                              void* d_out, int out_size, void* d_ws, size_t ws_size,
                              hipStream_t stream) {
    const float* x    = (const float*)d_in[0];
    const float* vals = (const float*)d_in[1];
    const float* W    = (const float*)d_in[2];
    const float* bias = (const float*)d_in[3];
    const int* rows   = (const int*)d_in[4];
    const int* cols   = (const int*)d_in[5];
    const int E = in_sizes[1];
    float* out = (float*)d_out;

    // workspace: i8 T0..T4, Tsc, Wq8, Wsc, edges, seq, CSR
    signed char* i8T = (signed char*)d_ws;                             // 5 * V*512
    float* Tsc = (float*)(i8T + (size_t)KORD * V_NODES * FDIM);        // 12*V + 64 pad
    signed char* Wq8 = (signed char*)(Tsc + 12 * (size_t)V_NODES + 64);   // 128*640
    float* Wsc = (float*)(Wq8 + (size_t)COUT * KTOT);                  // 640
    EPair* ep     = (EPair*)(Wsc + KORD * COUT);
    int*   seq    = (int*)(ep + E);           // E
    int*   rowPtr = seq + E;                  // V+1
    int*   cnt    = rowPtr + V_NODES + 1;     // V
    int*   blkSum = cnt + V_NODES;            // SCAN_NBLK

    signed char* i8T0 = i8T;
    signed char* i8T1 = i8T + 1 * (size_t)V_NODES * FDIM;
    signed char* i8T2 = i8T + 2 * (size_t)V_NODES * FDIM;
    signed char* i8T3 = i8T + 3 * (size_t)V_NODES * FDIM;
    signed char* i8T4 = i8T + 4 * (size_t)V_NODES * FDIM;
    float* scC = Tsc;                                  // [8][V] chunked T0 scales
    float* sc1 = Tsc + 8 * (size_t)V_NODES;
    float* sc2 = Tsc + 9 * (size_t)V_NODES;
    float* sc3 = Tsc + 10 * (size_t)V_NODES;
    float* sc4 = Tsc + 11 * (size_t)V_NODES;

    const int histBlocks = (E + 255) / 256;
    const int spB4 = (V_NODES + 3) / 4;

    // prep1: hist(+seq) ∥ convw_q8
    hipMemsetAsync(cnt, 0, V_NODES * sizeof(int), stream);
    prep1_kernel<<<histBlocks + CONVW_BLOCKS, 256, 0, stream>>>(
        rows, cnt, seq, E, histBlocks, W, Wq8, Wsc);
    scan1_kernel<<<SCAN_NBLK, 256, 0, stream>>>(cnt, rowPtr, blkSum);
    scan23_kernel<<<SCAN_NBLK, 256, 0, stream>>>(blkSum, rowPtr);
    // prep2: atomic-free scatter ∥ LDS-transpose quantize
    prep2_kernel<<<histBlocks + TQ2_BLOCKS, 256, 0, stream>>>(
        x, i8T0, scC, vals, rows, cols, rowPtr, seq, ep, E, histBlocks);

    // Chebyshev recurrence — i8 state; T0 chunked scales, T1.. per-row
    spmm_i8_kernel<<<spB4, 256, 0, stream>>>(ep, rowPtr, i8T0, scC, i8T0, scC, i8T1, sc1, 1.f, 0, 1, 0);
    spmm_i8_kernel<<<spB4, 256, 0, stream>>>(ep, rowPtr, i8T1, sc1, i8T0, scC, i8T2, sc2, 2.f, 1, 0, 1);
    spmm_i8_kernel<<<spB4, 256, 0, stream>>>(ep, rowPtr, i8T2, sc2, i8T1, sc1, i8T3, sc3, 2.f, 1, 0, 0);
    spmm_i8_kernel<<<spB4, 256, 0, stream>>>(ep, rowPtr, i8T3, sc3, i8T2, sc2, i8T4, sc4, 2.f, 1, 0, 0);

    // fused contraction over all 5 orders (i8 MFMA, 8 waves, hybrid rescale)
    dim3 gg((V_NODES + 127) / 128, BATCH);
    gemm_mfma_kernel<<<gg, 512, 0, stream>>>(i8T, Tsc, Wq8, Wsc, bias, out);
}